// Round 3
// baseline (3421.628 us; speedup 1.0000x reference)
//
#include <hip/hip_runtime.h>
#include <hip/hip_bf16.h>
#include <math.h>

// ---------------------------------------------------------------------------
// WNO1d. wave_conv(v) = v + Syn(W1*lo8-lo8, W2*hi8-hi8)  (perfect reconstruction,
// intermediate highs pass through). A (28x1024) and M^T (28x1024) are constant,
// computed on device. Layout vT[b][s][c].
// This round: register-cached weights + LDS-broadcast activations (lane = out
// channel), proj fused into layer/fc0 kernels, shuffle-reduce head.
// ---------------------------------------------------------------------------

#define BDIM 64
#define SLEN 1024
#define WCH  64
#define BC   (BDIM*WCH)

constexpr float RLv[12] = {
    0.11154074335008017f, 0.4946238903983854f, 0.7511339080215775f,
    0.3152503517092432f, -0.22626469396516913f, -0.12976686756709563f,
    0.09750160558707936f, 0.02752286553001629f, -0.031582039318031156f,
    0.0005538422009938016f, 0.004777257511010651f, -0.00107730108499558f };
constexpr float AHv[12] = {
     RLv[11], -RLv[10],  RLv[9], -RLv[8],  RLv[7], -RLv[6],
     RLv[5],  -RLv[4],   RLv[3], -RLv[2],  RLv[1], -RLv[0] };
constexpr float SLv[12] = {
     RLv[11], RLv[10], RLv[9], RLv[8], RLv[7], RLv[6],
     RLv[5],  RLv[4],  RLv[3], RLv[2], RLv[1], RLv[0] };
constexpr float SHv[12] = {
    -RLv[0],  RLv[1], -RLv[2],  RLv[3], -RLv[4],  RLv[5],
    -RLv[6],  RLv[7], -RLv[8],  RLv[9], -RLv[10], RLv[11] };

__device__ __forceinline__ float gelu_f(float x) {
    return 0.5f * x * (1.0f + erff(x * 0.7071067811865476f));
}

// ---------------------------------------------------------------------------
// Precompute A: Amat[x][s] (x<14 bottom lo row, x in [14,28) bottom hi row)
// ---------------------------------------------------------------------------
__global__ __launch_bounds__(256) void precompute_A_kernel(float* __restrict__ Amat)
{
    __shared__ float A[4][1024];
    __shared__ float Bf[4][520];
    const int t = threadIdx.x;
    const int l = t & 63;
    const int g = t >> 6;
    const int s0 = blockIdx.x * 4 + g;

    for (int i = l; i < SLEN; i += 64) A[g][i] = (i == s0) ? 1.0f : 0.0f;
    __syncthreads();

    const int NIN[8]  = {1024, 517, 264, 137, 74, 42, 26, 18};
    const int NOUT[8] = { 517, 264, 137,  74, 42, 26, 18, 14};

#pragma unroll
    for (int lev = 0; lev < 8; ++lev) {
        float* in  = (lev & 1) ? Bf[g] : A[g];
        float* out = (lev & 1) ? A[g] : Bf[g];
        const int nin = NIN[lev], nout = NOUT[lev];
        for (int m = l; m < nout; m += 64) {
            float alo = 0.f, ahi = 0.f;
#pragma unroll
            for (int tt = 0; tt < 12; ++tt) {
                int jj = 2 * m + tt - 10;
                if (jj < 0)         jj = -1 - jj;
                else if (jj >= nin) jj = 2 * nin - 1 - jj;
                float xv = in[jj];
                alo += xv * RLv[tt];
                if (lev == 7) ahi += xv * AHv[tt];
            }
            out[m] = alo;
            if (lev == 7) {
                Amat[m * SLEN + s0]        = alo;
                Amat[(14 + m) * SLEN + s0] = ahi;
            }
        }
        __syncthreads();
    }
}

// ---------------------------------------------------------------------------
// Precompute M^T: MmatT[u][s] = M[s][u]  (zero-hi synthesis of unit vector u)
// ---------------------------------------------------------------------------
__global__ __launch_bounds__(256) void precompute_M_kernel(float* __restrict__ MmatT)
{
    __shared__ float A[4][1024];
    __shared__ float Bf[4][520];
    __shared__ float hib[4][14];
    const int t = threadIdx.x;
    const int l = t & 63;
    const int g = t >> 6;
    const int u = blockIdx.x * 4 + g;

    if (l < 14) {
        A[g][l]   = (u < 14 && l == u) ? 1.0f : 0.0f;
        hib[g][l] = (u >= 14 && l == (u - 14)) ? 1.0f : 0.0f;
    }
    __syncthreads();

    const int NH[8] = {14, 18, 26, 42, 74, 137, 264, 517};
    const int NO[8] = {18, 26, 42, 74, 138, 264, 518, 1024};

#pragma unroll
    for (int s = 0; s < 8; ++s) {
        const float* lo = (s & 1) ? Bf[g] : A[g];
        float* out      = (s & 1) ? A[g] : Bf[g];
        const int N = NH[s], nout = NO[s];
        for (int m = l; m < nout; m += 64) {
            float acc = 0.f;
#pragma unroll
            for (int tt = 0; tt < 12; ++tt) {
                int uu = m + tt - 1;
                if ((uu & 1) == 0) {
                    int q = uu >> 1;
                    if (q < N) {
                        acc += lo[q] * SLv[tt];
                        if (s == 0) acc += hib[g][q] * SHv[tt];
                    }
                }
            }
            out[m] = acc;
        }
        __syncthreads();
    }
    for (int m = l; m < SLEN; m += 64) MmatT[u * SLEN + m] = A[g][m];
}

// ---------------------------------------------------------------------------
// fc0 (+ fused proj partial). grid = b*16 + tile. lane = c, wave w owns
// s-range [w*16, w*16+16).
// ---------------------------------------------------------------------------
__global__ __launch_bounds__(256) void fc0proj_kernel(
    const float* __restrict__ x, const float* __restrict__ fc0w,
    const float* __restrict__ fc0b, const float* __restrict__ Amat,
    float* __restrict__ vT, float* __restrict__ Ppart)
{
    __shared__ __align__(16) float At[28][68];
    __shared__ float red[28][64];
    const int t = threadIdx.x;
    const int c = t & 63;
    const int w = t >> 6;
    const int b    = blockIdx.x >> 4;
    const int tile = blockIdx.x & 15;
    const int s0   = tile << 6;

    for (int idx = t; idx < 28 * 64; idx += 256) {
        int xr = idx >> 6, s = idx & 63;
        At[xr][s] = Amat[xr * SLEN + s0 + s];
    }
    const float w0a = fc0w[c], w0b = fc0w[WCH + c], b0 = fc0b[c];
    __syncthreads();

    float vp[16];
#pragma unroll
    for (int k = 0; k < 16; ++k) {
        int s = s0 + (w << 4) + k;
        float xv = x[b * SLEN + s];
        vp[k] = xv * w0a + (float)s * (1.0f / 1023.0f) * w0b + b0;
    }
#pragma unroll
    for (int k = 0; k < 16; ++k)
        vT[((size_t)(b * SLEN + s0 + (w << 4) + k)) * 64 + c] = vp[k];

    float acc2[28];
#pragma unroll
    for (int xr = 0; xr < 28; ++xr) acc2[xr] = 0.f;
#pragma unroll
    for (int xr = 0; xr < 28; ++xr) {
        const float4* a4 = (const float4*)&At[xr][w << 4];
#pragma unroll
        for (int q = 0; q < 4; ++q) {
            float4 a = a4[q];
            acc2[xr] += vp[4*q+0]*a.x + vp[4*q+1]*a.y + vp[4*q+2]*a.z + vp[4*q+3]*a.w;
        }
    }
    // 4-pass wave reduction into red
    for (int ww = 0; ww < 4; ++ww) {
        if (w == ww) {
#pragma unroll
            for (int xr = 0; xr < 28; ++xr) {
                if (ww == 0) red[xr][c] = acc2[xr];
                else         red[xr][c] += acc2[xr];
            }
        }
        __syncthreads();
    }
    for (int idx = t; idx < 28 * 64; idx += 256) {
        int xr = idx >> 6, cc = idx & 63;
        Ppart[((size_t)((b * 16 + tile) * 28 + xr)) * 64 + cc] = red[xr][cc];
    }
}

// ---------------------------------------------------------------------------
// Mix: reduce Ppart over tiles -> LO[x][c]; D[x][o] = sum_i LO[x][i]*W[i][o][x]
//      - LO[x][o].  grid = x*8 + bt (224 blocks), 8 batches per block.
// ---------------------------------------------------------------------------
__global__ __launch_bounds__(256) void mix_kernel(
    const float* __restrict__ Ppart, const float* __restrict__ w1,
    const float* __restrict__ w2, float* __restrict__ D)
{
    __shared__ float Ws[64][65];
    __shared__ float LO[8][64];
    const int t = threadIdx.x;
    const int o = t & 63;
    const int w = t >> 6;
    const int x  = blockIdx.x >> 3;
    const int b0 = (blockIdx.x & 7) << 3;

    const float* wbase = (x < 14) ? w1 : w2;
    const int xi = (x < 14) ? x : (x - 14);
    for (int idx = t; idx < 4096; idx += 256)
        Ws[idx >> 6][idx & 63] = wbase[(size_t)idx * 14 + xi];

#pragma unroll
    for (int j = 0; j < 2; ++j) {
        int bi = w + 4 * j;
        float s = 0.f;
        for (int tile = 0; tile < 16; ++tile)
            s += Ppart[((size_t)(((b0 + bi) * 16 + tile) * 28 + x)) * 64 + o];
        LO[bi][o] = s;
    }
    __syncthreads();

#pragma unroll
    for (int j = 0; j < 2; ++j) {
        int bi = w + 4 * j;
        float acc = 0.f;
        for (int i = 0; i < 64; ++i)
            acc += LO[bi][i] * Ws[i][o];
        acc -= LO[bi][o];
        D[((size_t)((b0 + bi) * 28 + x)) * 64 + o] = acc;
    }
}

// ---------------------------------------------------------------------------
// Fused layer: v'[s][o] = act(v[s][o] + sum_c v[s][c]*cw[o][c] + cb[o]
//                              + sum_x D[x][o]*M[s][x])
// + fused proj partial for next layer.  grid = b*16 + tile. lane = o.
// Weights cw[o][:], D[:][o] in registers; v broadcast from LDS [c][s].
// ---------------------------------------------------------------------------
__global__ __launch_bounds__(256) void layer_kernel(
    const float* __restrict__ vT, const float* __restrict__ Dbuf,
    const float* __restrict__ MmatT, const float* __restrict__ Amat,
    const float* __restrict__ cw, const float* __restrict__ cb,
    float* __restrict__ vout, float* __restrict__ Ppart,
    int do_gelu, int do_proj)
{
    __shared__ __align__(16) float vt[64][68];   // [c][s]
    __shared__ __align__(16) float Mt[28][68];   // [x][s]
    __shared__ __align__(16) float At[28][68];   // [x][s]
    __shared__ float red[28][64];
    const int t = threadIdx.x;
    const int o = t & 63;
    const int w = t >> 6;
    const int b    = blockIdx.x >> 4;
    const int tile = blockIdx.x & 15;
    const int s0   = tile << 6;

    for (int idx = t; idx < 4096; idx += 256) {
        int s = idx >> 6, c = idx & 63;
        vt[c][s] = vT[((size_t)(b * SLEN + s0 + s)) * 64 + c];
    }
    for (int idx = t; idx < 28 * 64; idx += 256) {
        int xr = idx >> 6, s = idx & 63;
        Mt[xr][s] = MmatT[xr * SLEN + s0 + s];
        At[xr][s] = Amat[xr * SLEN + s0 + s];
    }

    // register-cached weights (fully unrolled -> static indexing)
    float cwReg[64];
#pragma unroll
    for (int i = 0; i < 16; ++i) {
        float4 wv = *(const float4*)&cw[o * 64 + 4 * i];
        cwReg[4*i+0] = wv.x; cwReg[4*i+1] = wv.y;
        cwReg[4*i+2] = wv.z; cwReg[4*i+3] = wv.w;
    }
    float Dreg[28];
#pragma unroll
    for (int xr = 0; xr < 28; ++xr)
        Dreg[xr] = Dbuf[((size_t)(b * 28 + xr)) * 64 + o];
    const float cbv = cb[o];
    __syncthreads();

    float acc[16];
#pragma unroll
    for (int k = 0; k < 16; ++k) acc[k] = cbv;

    // channel mix: broadcast v, register weights
#pragma unroll
    for (int c = 0; c < 64; ++c) {
        const float4* v4 = (const float4*)&vt[c][w << 4];
        float wv = cwReg[c];
#pragma unroll
        for (int q = 0; q < 4; ++q) {
            float4 v = v4[q];
            acc[4*q+0] += v.x * wv; acc[4*q+1] += v.y * wv;
            acc[4*q+2] += v.z * wv; acc[4*q+3] += v.w * wv;
        }
    }
    // M*D term
#pragma unroll
    for (int xr = 0; xr < 28; ++xr) {
        const float4* m4 = (const float4*)&Mt[xr][w << 4];
        float dv = Dreg[xr];
#pragma unroll
        for (int q = 0; q < 4; ++q) {
            float4 m = m4[q];
            acc[4*q+0] += m.x * dv; acc[4*q+1] += m.y * dv;
            acc[4*q+2] += m.z * dv; acc[4*q+3] += m.w * dv;
        }
    }
    // residual v[s][o] (per-lane LDS read) + activation + store
    float vp[16];
    {
        const float4* r4 = (const float4*)&vt[o][w << 4];
#pragma unroll
        for (int q = 0; q < 4; ++q) {
            float4 r = r4[q];
            vp[4*q+0] = acc[4*q+0] + r.x; vp[4*q+1] = acc[4*q+1] + r.y;
            vp[4*q+2] = acc[4*q+2] + r.z; vp[4*q+3] = acc[4*q+3] + r.w;
        }
    }
    if (do_gelu) {
#pragma unroll
        for (int k = 0; k < 16; ++k) vp[k] = gelu_f(vp[k]);
    }
#pragma unroll
    for (int k = 0; k < 16; ++k)
        vout[((size_t)(b * SLEN + s0 + (w << 4) + k)) * 64 + o] = vp[k];

    if (!do_proj) return;

    // proj partial for next layer
    float acc2[28];
#pragma unroll
    for (int xr = 0; xr < 28; ++xr) acc2[xr] = 0.f;
#pragma unroll
    for (int xr = 0; xr < 28; ++xr) {
        const float4* a4 = (const float4*)&At[xr][w << 4];
#pragma unroll
        for (int q = 0; q < 4; ++q) {
            float4 a = a4[q];
            acc2[xr] += vp[4*q+0]*a.x + vp[4*q+1]*a.y + vp[4*q+2]*a.z + vp[4*q+3]*a.w;
        }
    }
    for (int ww = 0; ww < 4; ++ww) {
        if (w == ww) {
#pragma unroll
            for (int xr = 0; xr < 28; ++xr) {
                if (ww == 0) red[xr][o] = acc2[xr];
                else         red[xr][o] += acc2[xr];
            }
        }
        __syncthreads();
    }
    for (int idx = t; idx < 28 * 64; idx += 256) {
        int xr = idx >> 6, cc = idx & 63;
        Ppart[((size_t)((b * 16 + tile) * 28 + xr)) * 64 + cc] = red[xr][cc];
    }
}

// ---------------------------------------------------------------------------
// Head: out[b,s] (+)= sum_h gelu(sum_c v[s][c]*fc1w[c][h] + fc1b[h])*fc2w[h] + fc2b
// grid = b*32 + tile32 (32 s per block). lane+64*(w&1) = h; (w>>1) = s half.
// fc1w column in registers, v broadcast, butterfly reduce over h.
// ---------------------------------------------------------------------------
__global__ __launch_bounds__(256) void head_kernel(
    const float* __restrict__ vT, const float* __restrict__ fc1w,
    const float* __restrict__ fc1b, const float* __restrict__ fc2w,
    const float* __restrict__ fc2b, float* __restrict__ out, int accumulate)
{
    __shared__ __align__(16) float vt[64][36];   // [c][s(32)]
    __shared__ float red[4][16];
    const int t = threadIdx.x;
    const int l = t & 63;
    const int w = t >> 6;
    const int h  = l + ((w & 1) << 6);
    const int sg = w >> 1;                        // 0/1 -> s-range sg*16..+16
    const int b    = blockIdx.x >> 5;
    const int tile = blockIdx.x & 31;
    const int s0   = tile << 5;

    for (int idx = t; idx < 2048; idx += 256) {
        int s = idx >> 6, c = idx & 63;
        vt[c][s] = vT[((size_t)(b * SLEN + s0 + s)) * 64 + c];
    }
    float w1reg[64];
#pragma unroll
    for (int c = 0; c < 64; ++c) w1reg[c] = fc1w[c * 128 + h];
    const float b1 = fc1b[h];
    const float w2v = fc2w[h];
    __syncthreads();

    float hid[16];
#pragma unroll
    for (int k = 0; k < 16; ++k) hid[k] = b1;
#pragma unroll
    for (int c = 0; c < 64; ++c) {
        const float4* v4 = (const float4*)&vt[c][sg << 4];
        float wv = w1reg[c];
#pragma unroll
        for (int q = 0; q < 4; ++q) {
            float4 v = v4[q];
            hid[4*q+0] += v.x * wv; hid[4*q+1] += v.y * wv;
            hid[4*q+2] += v.z * wv; hid[4*q+3] += v.w * wv;
        }
    }
    float u[16];
#pragma unroll
    for (int k = 0; k < 16; ++k) u[k] = gelu_f(hid[k]) * w2v;
    // butterfly sum over 64 lanes
#pragma unroll
    for (int k = 0; k < 16; ++k) {
#pragma unroll
        for (int m = 1; m < 64; m <<= 1)
            u[k] += __shfl_xor(u[k], m, 64);
    }
    if (l == 0) {
#pragma unroll
        for (int k = 0; k < 16; ++k) red[w][k] = u[k];
    }
    __syncthreads();
    if (t < 32) {
        int p = t >> 4, k = t & 15;
        int si = (p << 4) + k;                    // == t
        float sum = red[2*p][k] + red[2*p+1][k] + fc2b[0];
        size_t oidx = (size_t)b * SLEN + s0 + si;
        out[oidx] = accumulate ? (out[oidx] + sum) : sum;
    }
}

// ---------------------------------------------------------------------------
extern "C" void kernel_launch(void* const* d_in, const int* in_sizes, int n_in,
                              void* d_out, int out_size, void* d_ws, size_t ws_size,
                              hipStream_t stream)
{
    const float* x = (const float*)d_in[0];

    float* ws    = (float*)d_ws;
    float* vA    = ws;                                  // 4,194,304 f
    float* vB    = vA + (size_t)BC * SLEN;              // 4,194,304 f
    float* Amat  = vB + (size_t)BC * SLEN;              // 28,672 f
    float* MmatT = Amat + 28 * SLEN;                    // 28,672 f
    float* Ppart = MmatT + 28 * SLEN;                   // 1,835,008 f
    float* Dbuf  = Ppart + (size_t)BDIM * 16 * 28 * 64; // 114,688 f

    precompute_A_kernel<<<256, 256, 0, stream>>>(Amat);
    precompute_M_kernel<<<7, 256, 0, stream>>>(MmatT);

    for (int br = 0; br < 2; ++br) {
        const float* fc0w = (const float*)d_in[1 + br * 10 + 0];
        const float* fc0b = (const float*)d_in[1 + br * 10 + 1];
        const float* ww1  = (const float*)d_in[1 + br * 10 + 2];
        const float* ww2  = (const float*)d_in[1 + br * 10 + 3];
        const float* cw   = (const float*)d_in[1 + br * 10 + 4];
        const float* cb   = (const float*)d_in[1 + br * 10 + 5];
        const float* fc1w = (const float*)d_in[1 + br * 10 + 6];
        const float* fc1b = (const float*)d_in[1 + br * 10 + 7];
        const float* fc2w = (const float*)d_in[1 + br * 10 + 8];
        const float* fc2b = (const float*)d_in[1 + br * 10 + 9];

        float* pv = vA;
        float* pa = vB;

        fc0proj_kernel<<<BDIM * 16, 256, 0, stream>>>(x, fc0w, fc0b, Amat, pv, Ppart);

        for (int i = 0; i < 4; ++i) {
            mix_kernel<<<28 * 8, 256, 0, stream>>>(
                Ppart, ww1 + (size_t)i * WCH * WCH * 14,
                ww2 + (size_t)i * WCH * WCH * 14, Dbuf);
            layer_kernel<<<BDIM * 16, 256, 0, stream>>>(
                pv, Dbuf, MmatT, Amat, cw + (size_t)i * WCH * WCH,
                cb + (size_t)i * WCH, pa, Ppart,
                (i < 3) ? 1 : 0, (i < 3) ? 1 : 0);
            float* tmp = pv; pv = pa; pa = tmp;
        }

        head_kernel<<<BDIM * 32, 256, 0, stream>>>(
            pv, fc1w, fc1b, fc2w, fc2b, (float*)d_out, br);
    }
}

// Round 4
// 588.813 us; speedup vs baseline: 5.8111x; 5.8111x over previous
//
#include <hip/hip_runtime.h>
#include <hip/hip_bf16.h>
#include <math.h>

// ---------------------------------------------------------------------------
// WNO1d. wave_conv(v) = v + Syn(W1*lo8-lo8, W2*hi8-hi8)  (perfect reconstruction,
// intermediate highs pass through). A (28x1024) and M^T (28x1024) are constant,
// computed on device. Layout vT[b][s][c].
// Round 4: round-3 pipeline, head reverted to round-2 structure (round-3 head
// spilled: VGPR=256, 1.9GB scratch FETCH).
// ---------------------------------------------------------------------------

#define BDIM 64
#define SLEN 1024
#define WCH  64
#define BC   (BDIM*WCH)

constexpr float RLv[12] = {
    0.11154074335008017f, 0.4946238903983854f, 0.7511339080215775f,
    0.3152503517092432f, -0.22626469396516913f, -0.12976686756709563f,
    0.09750160558707936f, 0.02752286553001629f, -0.031582039318031156f,
    0.0005538422009938016f, 0.004777257511010651f, -0.00107730108499558f };
constexpr float AHv[12] = {
     RLv[11], -RLv[10],  RLv[9], -RLv[8],  RLv[7], -RLv[6],
     RLv[5],  -RLv[4],   RLv[3], -RLv[2],  RLv[1], -RLv[0] };
constexpr float SLv[12] = {
     RLv[11], RLv[10], RLv[9], RLv[8], RLv[7], RLv[6],
     RLv[5],  RLv[4],  RLv[3], RLv[2], RLv[1], RLv[0] };
constexpr float SHv[12] = {
    -RLv[0],  RLv[1], -RLv[2],  RLv[3], -RLv[4],  RLv[5],
    -RLv[6],  RLv[7], -RLv[8],  RLv[9], -RLv[10], RLv[11] };

__device__ __forceinline__ float gelu_f(float x) {
    return 0.5f * x * (1.0f + erff(x * 0.7071067811865476f));
}

// ---------------------------------------------------------------------------
__global__ __launch_bounds__(256) void precompute_A_kernel(float* __restrict__ Amat)
{
    __shared__ float A[4][1024];
    __shared__ float Bf[4][520];
    const int t = threadIdx.x;
    const int l = t & 63;
    const int g = t >> 6;
    const int s0 = blockIdx.x * 4 + g;

    for (int i = l; i < SLEN; i += 64) A[g][i] = (i == s0) ? 1.0f : 0.0f;
    __syncthreads();

    const int NIN[8]  = {1024, 517, 264, 137, 74, 42, 26, 18};
    const int NOUT[8] = { 517, 264, 137,  74, 42, 26, 18, 14};

#pragma unroll
    for (int lev = 0; lev < 8; ++lev) {
        float* in  = (lev & 1) ? Bf[g] : A[g];
        float* out = (lev & 1) ? A[g] : Bf[g];
        const int nin = NIN[lev], nout = NOUT[lev];
        for (int m = l; m < nout; m += 64) {
            float alo = 0.f, ahi = 0.f;
#pragma unroll
            for (int tt = 0; tt < 12; ++tt) {
                int jj = 2 * m + tt - 10;
                if (jj < 0)         jj = -1 - jj;
                else if (jj >= nin) jj = 2 * nin - 1 - jj;
                float xv = in[jj];
                alo += xv * RLv[tt];
                if (lev == 7) ahi += xv * AHv[tt];
            }
            out[m] = alo;
            if (lev == 7) {
                Amat[m * SLEN + s0]        = alo;
                Amat[(14 + m) * SLEN + s0] = ahi;
            }
        }
        __syncthreads();
    }
}

// ---------------------------------------------------------------------------
__global__ __launch_bounds__(256) void precompute_M_kernel(float* __restrict__ MmatT)
{
    __shared__ float A[4][1024];
    __shared__ float Bf[4][520];
    __shared__ float hib[4][14];
    const int t = threadIdx.x;
    const int l = t & 63;
    const int g = t >> 6;
    const int u = blockIdx.x * 4 + g;

    if (l < 14) {
        A[g][l]   = (u < 14 && l == u) ? 1.0f : 0.0f;
        hib[g][l] = (u >= 14 && l == (u - 14)) ? 1.0f : 0.0f;
    }
    __syncthreads();

    const int NH[8] = {14, 18, 26, 42, 74, 137, 264, 517};
    const int NO[8] = {18, 26, 42, 74, 138, 264, 518, 1024};

#pragma unroll
    for (int s = 0; s < 8; ++s) {
        const float* lo = (s & 1) ? Bf[g] : A[g];
        float* out      = (s & 1) ? A[g] : Bf[g];
        const int N = NH[s], nout = NO[s];
        for (int m = l; m < nout; m += 64) {
            float acc = 0.f;
#pragma unroll
            for (int tt = 0; tt < 12; ++tt) {
                int uu = m + tt - 1;
                if ((uu & 1) == 0) {
                    int q = uu >> 1;
                    if (q < N) {
                        acc += lo[q] * SLv[tt];
                        if (s == 0) acc += hib[g][q] * SHv[tt];
                    }
                }
            }
            out[m] = acc;
        }
        __syncthreads();
    }
    for (int m = l; m < SLEN; m += 64) MmatT[u * SLEN + m] = A[g][m];
}

// ---------------------------------------------------------------------------
// fc0 (+ fused proj partial). grid = b*16 + tile. lane = c, wave w owns
// s-range [w*16, w*16+16).
// ---------------------------------------------------------------------------
__global__ __launch_bounds__(256) void fc0proj_kernel(
    const float* __restrict__ x, const float* __restrict__ fc0w,
    const float* __restrict__ fc0b, const float* __restrict__ Amat,
    float* __restrict__ vT, float* __restrict__ Ppart)
{
    __shared__ __align__(16) float At[28][68];
    __shared__ float red[28][64];
    const int t = threadIdx.x;
    const int c = t & 63;
    const int w = t >> 6;
    const int b    = blockIdx.x >> 4;
    const int tile = blockIdx.x & 15;
    const int s0   = tile << 6;

    for (int idx = t; idx < 28 * 64; idx += 256) {
        int xr = idx >> 6, s = idx & 63;
        At[xr][s] = Amat[xr * SLEN + s0 + s];
    }
    const float w0a = fc0w[c], w0b = fc0w[WCH + c], b0 = fc0b[c];
    __syncthreads();

    float vp[16];
#pragma unroll
    for (int k = 0; k < 16; ++k) {
        int s = s0 + (w << 4) + k;
        float xv = x[b * SLEN + s];
        vp[k] = xv * w0a + (float)s * (1.0f / 1023.0f) * w0b + b0;
    }
#pragma unroll
    for (int k = 0; k < 16; ++k)
        vT[((size_t)(b * SLEN + s0 + (w << 4) + k)) * 64 + c] = vp[k];

    float acc2[28];
#pragma unroll
    for (int xr = 0; xr < 28; ++xr) acc2[xr] = 0.f;
#pragma unroll
    for (int xr = 0; xr < 28; ++xr) {
        const float4* a4 = (const float4*)&At[xr][w << 4];
#pragma unroll
        for (int q = 0; q < 4; ++q) {
            float4 a = a4[q];
            acc2[xr] += vp[4*q+0]*a.x + vp[4*q+1]*a.y + vp[4*q+2]*a.z + vp[4*q+3]*a.w;
        }
    }
    for (int ww = 0; ww < 4; ++ww) {
        if (w == ww) {
#pragma unroll
            for (int xr = 0; xr < 28; ++xr) {
                if (ww == 0) red[xr][c] = acc2[xr];
                else         red[xr][c] += acc2[xr];
            }
        }
        __syncthreads();
    }
    for (int idx = t; idx < 28 * 64; idx += 256) {
        int xr = idx >> 6, cc = idx & 63;
        Ppart[((size_t)((b * 16 + tile) * 28 + xr)) * 64 + cc] = red[xr][cc];
    }
}

// ---------------------------------------------------------------------------
// Mix: reduce Ppart over tiles -> LO[x][c]; D[x][o] = sum_i LO[x][i]*W[i][o][x]
//      - LO[x][o].  grid = x*8 + bt (224 blocks), 8 batches per block.
// ---------------------------------------------------------------------------
__global__ __launch_bounds__(256) void mix_kernel(
    const float* __restrict__ Ppart, const float* __restrict__ w1,
    const float* __restrict__ w2, float* __restrict__ D)
{
    __shared__ float Ws[64][65];
    __shared__ float LO[8][64];
    const int t = threadIdx.x;
    const int o = t & 63;
    const int w = t >> 6;
    const int x  = blockIdx.x >> 3;
    const int b0 = (blockIdx.x & 7) << 3;

    const float* wbase = (x < 14) ? w1 : w2;
    const int xi = (x < 14) ? x : (x - 14);
    for (int idx = t; idx < 4096; idx += 256)
        Ws[idx >> 6][idx & 63] = wbase[(size_t)idx * 14 + xi];

#pragma unroll
    for (int j = 0; j < 2; ++j) {
        int bi = w + 4 * j;
        float s = 0.f;
        for (int tile = 0; tile < 16; ++tile)
            s += Ppart[((size_t)(((b0 + bi) * 16 + tile) * 28 + x)) * 64 + o];
        LO[bi][o] = s;
    }
    __syncthreads();

#pragma unroll
    for (int j = 0; j < 2; ++j) {
        int bi = w + 4 * j;
        float acc = 0.f;
        for (int i = 0; i < 64; ++i)
            acc += LO[bi][i] * Ws[i][o];
        acc -= LO[bi][o];
        D[((size_t)((b0 + bi) * 28 + x)) * 64 + o] = acc;
    }
}

// ---------------------------------------------------------------------------
// Fused layer: v'[s][o] = act(v[s][o] + sum_c v[s][c]*cw[o][c] + cb[o]
//                              + sum_x D[x][o]*M[s][x])
// + fused proj partial for next layer.  grid = b*16 + tile. lane = o.
// ---------------------------------------------------------------------------
__global__ __launch_bounds__(256) void layer_kernel(
    const float* __restrict__ vT, const float* __restrict__ Dbuf,
    const float* __restrict__ MmatT, const float* __restrict__ Amat,
    const float* __restrict__ cw, const float* __restrict__ cb,
    float* __restrict__ vout, float* __restrict__ Ppart,
    int do_gelu, int do_proj)
{
    __shared__ __align__(16) float vt[64][68];   // [c][s]
    __shared__ __align__(16) float Mt[28][68];   // [x][s]
    __shared__ __align__(16) float At[28][68];   // [x][s]
    __shared__ float red[28][64];
    const int t = threadIdx.x;
    const int o = t & 63;
    const int w = t >> 6;
    const int b    = blockIdx.x >> 4;
    const int tile = blockIdx.x & 15;
    const int s0   = tile << 6;

    for (int idx = t; idx < 4096; idx += 256) {
        int s = idx >> 6, c = idx & 63;
        vt[c][s] = vT[((size_t)(b * SLEN + s0 + s)) * 64 + c];
    }
    for (int idx = t; idx < 28 * 64; idx += 256) {
        int xr = idx >> 6, s = idx & 63;
        Mt[xr][s] = MmatT[xr * SLEN + s0 + s];
        At[xr][s] = Amat[xr * SLEN + s0 + s];
    }

    float cwReg[64];
#pragma unroll
    for (int i = 0; i < 16; ++i) {
        float4 wv = *(const float4*)&cw[o * 64 + 4 * i];
        cwReg[4*i+0] = wv.x; cwReg[4*i+1] = wv.y;
        cwReg[4*i+2] = wv.z; cwReg[4*i+3] = wv.w;
    }
    float Dreg[28];
#pragma unroll
    for (int xr = 0; xr < 28; ++xr)
        Dreg[xr] = Dbuf[((size_t)(b * 28 + xr)) * 64 + o];
    const float cbv = cb[o];
    __syncthreads();

    float acc[16];
#pragma unroll
    for (int k = 0; k < 16; ++k) acc[k] = cbv;

#pragma unroll
    for (int c = 0; c < 64; ++c) {
        const float4* v4 = (const float4*)&vt[c][w << 4];
        float wv = cwReg[c];
#pragma unroll
        for (int q = 0; q < 4; ++q) {
            float4 v = v4[q];
            acc[4*q+0] += v.x * wv; acc[4*q+1] += v.y * wv;
            acc[4*q+2] += v.z * wv; acc[4*q+3] += v.w * wv;
        }
    }
#pragma unroll
    for (int xr = 0; xr < 28; ++xr) {
        const float4* m4 = (const float4*)&Mt[xr][w << 4];
        float dv = Dreg[xr];
#pragma unroll
        for (int q = 0; q < 4; ++q) {
            float4 m = m4[q];
            acc[4*q+0] += m.x * dv; acc[4*q+1] += m.y * dv;
            acc[4*q+2] += m.z * dv; acc[4*q+3] += m.w * dv;
        }
    }
    float vp[16];
    {
        const float4* r4 = (const float4*)&vt[o][w << 4];
#pragma unroll
        for (int q = 0; q < 4; ++q) {
            float4 r = r4[q];
            vp[4*q+0] = acc[4*q+0] + r.x; vp[4*q+1] = acc[4*q+1] + r.y;
            vp[4*q+2] = acc[4*q+2] + r.z; vp[4*q+3] = acc[4*q+3] + r.w;
        }
    }
    if (do_gelu) {
#pragma unroll
        for (int k = 0; k < 16; ++k) vp[k] = gelu_f(vp[k]);
    }
#pragma unroll
    for (int k = 0; k < 16; ++k)
        vout[((size_t)(b * SLEN + s0 + (w << 4) + k)) * 64 + o] = vp[k];

    if (!do_proj) return;

    float acc2[28];
#pragma unroll
    for (int xr = 0; xr < 28; ++xr) acc2[xr] = 0.f;
#pragma unroll
    for (int xr = 0; xr < 28; ++xr) {
        const float4* a4 = (const float4*)&At[xr][w << 4];
#pragma unroll
        for (int q = 0; q < 4; ++q) {
            float4 a = a4[q];
            acc2[xr] += vp[4*q+0]*a.x + vp[4*q+1]*a.y + vp[4*q+2]*a.z + vp[4*q+3]*a.w;
        }
    }
    for (int ww = 0; ww < 4; ++ww) {
        if (w == ww) {
#pragma unroll
            for (int xr = 0; xr < 28; ++xr) {
                if (ww == 0) red[xr][o] = acc2[xr];
                else         red[xr][o] += acc2[xr];
            }
        }
        __syncthreads();
    }
    for (int idx = t; idx < 28 * 64; idx += 256) {
        int xr = idx >> 6, cc = idx & 63;
        Ppart[((size_t)((b * 16 + tile) * 28 + xr)) * 64 + cc] = red[xr][cc];
    }
}

// ---------------------------------------------------------------------------
// Head (round-2 proven structure): lane j = s, wave w owns 32 hidden units.
// fc1w in LDS (wave-broadcast float4 reads), hid[32] in registers.
// ---------------------------------------------------------------------------
__global__ __launch_bounds__(256) void head_kernel(
    const float* __restrict__ vT, const float* __restrict__ fc1w,
    const float* __restrict__ fc1b, const float* __restrict__ fc2w,
    const float* __restrict__ fc2b, float* __restrict__ out, int accumulate)
{
    __shared__ __align__(16) float vt[64][65];    // [s][c]
    __shared__ __align__(16) float fw[64][128];   // [c][h]
    __shared__ float red[4][64];
    const int t = threadIdx.x;
    const int j = t & 63;
    const int w = t >> 6;
    const int b  = blockIdx.x >> 4;
    const int s0 = (blockIdx.x & 15) << 6;

    for (int idx = t; idx < 4096; idx += 256) {
        int si = idx >> 6, cc = idx & 63;
        vt[si][cc] = vT[((size_t)(b * SLEN + s0 + si)) * 64 + cc];
    }
    for (int idx = t; idx < 8192; idx += 256)
        fw[idx >> 7][idx & 127] = fc1w[idx];
    __syncthreads();

    float hid[32];
#pragma unroll
    for (int hh = 0; hh < 32; ++hh) hid[hh] = fc1b[(w << 5) + hh];

    for (int cc = 0; cc < 64; ++cc) {
        float val = vt[j][cc];
        const float4* f4 = (const float4*)&fw[cc][w << 5];
#pragma unroll
        for (int i = 0; i < 8; ++i) {
            float4 f = f4[i];
            hid[4 * i + 0] += val * f.x;
            hid[4 * i + 1] += val * f.y;
            hid[4 * i + 2] += val * f.z;
            hid[4 * i + 3] += val * f.w;
        }
    }
    float partial = 0.f;
#pragma unroll
    for (int hh = 0; hh < 32; ++hh)
        partial += gelu_f(hid[hh]) * fc2w[(w << 5) + hh];

    red[w][j] = partial;
    __syncthreads();
    if (w == 0) {
        float sum = red[0][j] + red[1][j] + red[2][j] + red[3][j] + fc2b[0];
        size_t oidx = (size_t)b * SLEN + s0 + j;
        out[oidx] = accumulate ? (out[oidx] + sum) : sum;
    }
}

// ---------------------------------------------------------------------------
extern "C" void kernel_launch(void* const* d_in, const int* in_sizes, int n_in,
                              void* d_out, int out_size, void* d_ws, size_t ws_size,
                              hipStream_t stream)
{
    const float* x = (const float*)d_in[0];

    float* ws    = (float*)d_ws;
    float* vA    = ws;                                  // 4,194,304 f
    float* vB    = vA + (size_t)BC * SLEN;              // 4,194,304 f
    float* Amat  = vB + (size_t)BC * SLEN;              // 28,672 f
    float* MmatT = Amat + 28 * SLEN;                    // 28,672 f
    float* Ppart = MmatT + 28 * SLEN;                   // 1,835,008 f
    float* Dbuf  = Ppart + (size_t)BDIM * 16 * 28 * 64; // 114,688 f

    precompute_A_kernel<<<256, 256, 0, stream>>>(Amat);
    precompute_M_kernel<<<7, 256, 0, stream>>>(MmatT);

    for (int br = 0; br < 2; ++br) {
        const float* fc0w = (const float*)d_in[1 + br * 10 + 0];
        const float* fc0b = (const float*)d_in[1 + br * 10 + 1];
        const float* ww1  = (const float*)d_in[1 + br * 10 + 2];
        const float* ww2  = (const float*)d_in[1 + br * 10 + 3];
        const float* cw   = (const float*)d_in[1 + br * 10 + 4];
        const float* cb   = (const float*)d_in[1 + br * 10 + 5];
        const float* fc1w = (const float*)d_in[1 + br * 10 + 6];
        const float* fc1b = (const float*)d_in[1 + br * 10 + 7];
        const float* fc2w = (const float*)d_in[1 + br * 10 + 8];
        const float* fc2b = (const float*)d_in[1 + br * 10 + 9];

        float* pv = vA;
        float* pa = vB;

        fc0proj_kernel<<<BDIM * 16, 256, 0, stream>>>(x, fc0w, fc0b, Amat, pv, Ppart);

        for (int i = 0; i < 4; ++i) {
            mix_kernel<<<28 * 8, 256, 0, stream>>>(
                Ppart, ww1 + (size_t)i * WCH * WCH * 14,
                ww2 + (size_t)i * WCH * WCH * 14, Dbuf);
            layer_kernel<<<BDIM * 16, 256, 0, stream>>>(
                pv, Dbuf, MmatT, Amat, cw + (size_t)i * WCH * WCH,
                cb + (size_t)i * WCH, pa, Ppart,
                (i < 3) ? 1 : 0, (i < 3) ? 1 : 0);
            float* tmp = pv; pv = pa; pa = tmp;
        }

        head_kernel<<<BDIM * 16, 256, 0, stream>>>(
            pv, fc1w, fc1b, fc2w, fc2b, (float*)d_out, br);
    }
}

// Round 5
// 477.676 us; speedup vs baseline: 7.1631x; 1.2327x over previous
//
#include <hip/hip_runtime.h>
#include <hip/hip_bf16.h>
#include <math.h>

// ---------------------------------------------------------------------------
// WNO1d. wave_conv(v) = v + Syn(W1*lo8-lo8, W2*hi8-hi8)  (perfect reconstruction,
// intermediate highs pass through). A (28x1024) and M^T (28x1024) are constant,
// computed on device. Layout vT[b][s][c].
// Round 5: layer/head as fp32 register-tiled GEMMs (4x4 / 4x8 tiles), residual
// baked into transposed cw (+I) produced by a spare block of mix_kernel.
// Fused k=92: rows 0..63 = channel mix, rows 64..91 = M x D term.
// ---------------------------------------------------------------------------

#define BDIM 64
#define SLEN 1024
#define WCH  64
#define BC   (BDIM*WCH)

constexpr float RLv[12] = {
    0.11154074335008017f, 0.4946238903983854f, 0.7511339080215775f,
    0.3152503517092432f, -0.22626469396516913f, -0.12976686756709563f,
    0.09750160558707936f, 0.02752286553001629f, -0.031582039318031156f,
    0.0005538422009938016f, 0.004777257511010651f, -0.00107730108499558f };
constexpr float AHv[12] = {
     RLv[11], -RLv[10],  RLv[9], -RLv[8],  RLv[7], -RLv[6],
     RLv[5],  -RLv[4],   RLv[3], -RLv[2],  RLv[1], -RLv[0] };
constexpr float SLv[12] = {
     RLv[11], RLv[10], RLv[9], RLv[8], RLv[7], RLv[6],
     RLv[5],  RLv[4],  RLv[3], RLv[2], RLv[1], RLv[0] };
constexpr float SHv[12] = {
    -RLv[0],  RLv[1], -RLv[2],  RLv[3], -RLv[4],  RLv[5],
    -RLv[6],  RLv[7], -RLv[8],  RLv[9], -RLv[10], RLv[11] };

__device__ __forceinline__ float gelu_f(float x) {
    return 0.5f * x * (1.0f + erff(x * 0.7071067811865476f));
}

// ---------------------------------------------------------------------------
__global__ __launch_bounds__(256) void precompute_A_kernel(float* __restrict__ Amat)
{
    __shared__ float A[4][1024];
    __shared__ float Bf[4][520];
    const int t = threadIdx.x;
    const int l = t & 63;
    const int g = t >> 6;
    const int s0 = blockIdx.x * 4 + g;

    for (int i = l; i < SLEN; i += 64) A[g][i] = (i == s0) ? 1.0f : 0.0f;
    __syncthreads();

    const int NIN[8]  = {1024, 517, 264, 137, 74, 42, 26, 18};
    const int NOUT[8] = { 517, 264, 137,  74, 42, 26, 18, 14};

#pragma unroll
    for (int lev = 0; lev < 8; ++lev) {
        float* in  = (lev & 1) ? Bf[g] : A[g];
        float* out = (lev & 1) ? A[g] : Bf[g];
        const int nin = NIN[lev], nout = NOUT[lev];
        for (int m = l; m < nout; m += 64) {
            float alo = 0.f, ahi = 0.f;
#pragma unroll
            for (int tt = 0; tt < 12; ++tt) {
                int jj = 2 * m + tt - 10;
                if (jj < 0)         jj = -1 - jj;
                else if (jj >= nin) jj = 2 * nin - 1 - jj;
                float xv = in[jj];
                alo += xv * RLv[tt];
                if (lev == 7) ahi += xv * AHv[tt];
            }
            out[m] = alo;
            if (lev == 7) {
                Amat[m * SLEN + s0]        = alo;
                Amat[(14 + m) * SLEN + s0] = ahi;
            }
        }
        __syncthreads();
    }
}

// ---------------------------------------------------------------------------
__global__ __launch_bounds__(256) void precompute_M_kernel(float* __restrict__ MmatT)
{
    __shared__ float A[4][1024];
    __shared__ float Bf[4][520];
    __shared__ float hib[4][14];
    const int t = threadIdx.x;
    const int l = t & 63;
    const int g = t >> 6;
    const int u = blockIdx.x * 4 + g;

    if (l < 14) {
        A[g][l]   = (u < 14 && l == u) ? 1.0f : 0.0f;
        hib[g][l] = (u >= 14 && l == (u - 14)) ? 1.0f : 0.0f;
    }
    __syncthreads();

    const int NH[8] = {14, 18, 26, 42, 74, 137, 264, 517};
    const int NO[8] = {18, 26, 42, 74, 138, 264, 518, 1024};

#pragma unroll
    for (int s = 0; s < 8; ++s) {
        const float* lo = (s & 1) ? Bf[g] : A[g];
        float* out      = (s & 1) ? A[g] : Bf[g];
        const int N = NH[s], nout = NO[s];
        for (int m = l; m < nout; m += 64) {
            float acc = 0.f;
#pragma unroll
            for (int tt = 0; tt < 12; ++tt) {
                int uu = m + tt - 1;
                if ((uu & 1) == 0) {
                    int q = uu >> 1;
                    if (q < N) {
                        acc += lo[q] * SLv[tt];
                        if (s == 0) acc += hib[g][q] * SHv[tt];
                    }
                }
            }
            out[m] = acc;
        }
        __syncthreads();
    }
    for (int m = l; m < SLEN; m += 64) MmatT[u * SLEN + m] = A[g][m];
}

// ---------------------------------------------------------------------------
// fc0 (+ fused proj partial). grid = b*16 + tile. lane = c, wave w owns
// s-range [w*16, w*16+16).
// ---------------------------------------------------------------------------
__global__ __launch_bounds__(256) void fc0proj_kernel(
    const float* __restrict__ x, const float* __restrict__ fc0w,
    const float* __restrict__ fc0b, const float* __restrict__ Amat,
    float* __restrict__ vT, float* __restrict__ Ppart)
{
    __shared__ __align__(16) float At[28][68];
    __shared__ float red[28][64];
    const int t = threadIdx.x;
    const int c = t & 63;
    const int w = t >> 6;
    const int b    = blockIdx.x >> 4;
    const int tile = blockIdx.x & 15;
    const int s0   = tile << 6;

    for (int idx = t; idx < 28 * 64; idx += 256) {
        int xr = idx >> 6, s = idx & 63;
        At[xr][s] = Amat[xr * SLEN + s0 + s];
    }
    const float w0a = fc0w[c], w0b = fc0w[WCH + c], b0 = fc0b[c];
    __syncthreads();

    float vp[16];
#pragma unroll
    for (int k = 0; k < 16; ++k) {
        int s = s0 + (w << 4) + k;
        float xv = x[b * SLEN + s];
        vp[k] = xv * w0a + (float)s * (1.0f / 1023.0f) * w0b + b0;
    }
#pragma unroll
    for (int k = 0; k < 16; ++k)
        vT[((size_t)(b * SLEN + s0 + (w << 4) + k)) * 64 + c] = vp[k];

    float acc2[28];
#pragma unroll
    for (int xr = 0; xr < 28; ++xr) acc2[xr] = 0.f;
#pragma unroll
    for (int xr = 0; xr < 28; ++xr) {
        const float4* a4 = (const float4*)&At[xr][w << 4];
#pragma unroll
        for (int q = 0; q < 4; ++q) {
            float4 a = a4[q];
            acc2[xr] += vp[4*q+0]*a.x + vp[4*q+1]*a.y + vp[4*q+2]*a.z + vp[4*q+3]*a.w;
        }
    }
    for (int ww = 0; ww < 4; ++ww) {
        if (w == ww) {
#pragma unroll
            for (int xr = 0; xr < 28; ++xr) {
                if (ww == 0) red[xr][c] = acc2[xr];
                else         red[xr][c] += acc2[xr];
            }
        }
        __syncthreads();
    }
    for (int idx = t; idx < 28 * 64; idx += 256) {
        int xr = idx >> 6, cc = idx & 63;
        Ppart[((size_t)((b * 16 + tile) * 28 + xr)) * 64 + cc] = red[xr][cc];
    }
}

// ---------------------------------------------------------------------------
// Mix: reduce Ppart over tiles -> LO; D[x][o] = sum_i LO[x][i]*W[i][o][x]
//      - LO[x][o].  Blocks 0..223: mix. Block 224: cwT[k][o] = cw[o][k] + I.
// ---------------------------------------------------------------------------
__global__ __launch_bounds__(256) void mix_kernel(
    const float* __restrict__ Ppart, const float* __restrict__ w1,
    const float* __restrict__ w2, const float* __restrict__ cw,
    float* __restrict__ D, float* __restrict__ cwT)
{
    const int t = threadIdx.x;
    if (blockIdx.x == 224) {
        for (int idx = t; idx < 4096; idx += 256) {
            int k = idx >> 6, o = idx & 63;
            float val = cw[o * 64 + k];
            if (k == o) val += 1.0f;
            cwT[idx] = val;
        }
        return;
    }
    __shared__ float Ws[64][65];
    __shared__ float LO[8][64];
    const int o = t & 63;
    const int w = t >> 6;
    const int x  = blockIdx.x >> 3;
    const int b0 = (blockIdx.x & 7) << 3;

    const float* wbase = (x < 14) ? w1 : w2;
    const int xi = (x < 14) ? x : (x - 14);
    for (int idx = t; idx < 4096; idx += 256)
        Ws[idx >> 6][idx & 63] = wbase[(size_t)idx * 14 + xi];

#pragma unroll
    for (int j = 0; j < 2; ++j) {
        int bi = w + 4 * j;
        float s = 0.f;
        for (int tile = 0; tile < 16; ++tile)
            s += Ppart[((size_t)(((b0 + bi) * 16 + tile) * 28 + x)) * 64 + o];
        LO[bi][o] = s;
    }
    __syncthreads();

#pragma unroll
    for (int j = 0; j < 2; ++j) {
        int bi = w + 4 * j;
        float acc = 0.f;
        for (int i = 0; i < 64; ++i)
            acc += LO[bi][i] * Ws[i][o];
        acc -= LO[bi][o];
        D[((size_t)((b0 + bi) * 28 + x)) * 64 + o] = acc;
    }
}

// ---------------------------------------------------------------------------
// Fused layer, register-tiled GEMM (4s x 4o per thread, k = 92):
//   v'[s][o] = act( sum_{k<64} v[s][k]*(cwT[k][o]) + sum_{x} M[s][x]*D[x][o]
//              + cb[o] )           (residual baked into cwT via +I)
// + proj partial for next layer.  grid = b*16 + tile (64 s per block).
// LDS pool: vt 92x68 (v rows + M rows), wt 92x64 (cwT rows + D rows);
// after GEMM, wt is re-used for At (28x68) and red (28x64).
// ---------------------------------------------------------------------------
__global__ __launch_bounds__(256) void layer_kernel(
    const float* __restrict__ vT, const float* __restrict__ Dbuf,
    const float* __restrict__ MmatT, const float* __restrict__ Amat,
    const float* __restrict__ cwT, const float* __restrict__ cb,
    float* __restrict__ vout, float* __restrict__ Ppart,
    int do_gelu, int do_proj)
{
    __shared__ __align__(16) float pool[92 * 68 + 92 * 64];
    float* vt = pool;              // pitch 68, 92 rows
    float* wt = pool + 92 * 68;    // pitch 64, 92 rows
    float* At  = wt;               // pitch 68, 28 rows (alias, post-GEMM)
    float* red = wt + 28 * 68;     // 28 x 64       (alias, post-GEMM)

    const int t = threadIdx.x;
    const int b    = blockIdx.x >> 4;
    const int tile = blockIdx.x & 15;
    const int s0   = tile << 6;
    const size_t bS = (size_t)b * SLEN;

    // ---- stage ----
    for (int idx = t; idx < 4096; idx += 256) {        // v rows (transposed)
        int s = idx >> 6, c = idx & 63;
        vt[c * 68 + s] = vT[(bS + s0 + s) * 64 + c];
    }
    for (int idx = t; idx < 28 * 64; idx += 256) {     // M rows
        int xr = idx >> 6, s = idx & 63;
        vt[(64 + xr) * 68 + s] = MmatT[xr * SLEN + s0 + s];
    }
    for (int idx = t; idx < 1024; idx += 256)          // cwT rows (linear)
        ((float4*)wt)[idx] = ((const float4*)cwT)[idx];
    for (int idx = t; idx < 448; idx += 256)           // D rows (linear)
        ((float4*)(wt + 64 * 64))[idx] = ((const float4*)(Dbuf + (size_t)b * 28 * 64))[idx];
    __syncthreads();

    // ---- register-tiled GEMM ----
    const int sb = (t >> 4) * 4;       // s_local base (0..60)
    const int ob = (t & 15) * 4;       // o base (0..60)

    float4 cb4 = *(const float4*)&cb[ob];
    float acc[4][4];
#pragma unroll
    for (int i = 0; i < 4; ++i) {
        acc[i][0] = cb4.x; acc[i][1] = cb4.y; acc[i][2] = cb4.z; acc[i][3] = cb4.w;
    }

#pragma unroll 4
    for (int k = 0; k < 92; ++k) {
        float4 v4 = *(const float4*)&vt[k * 68 + sb];
        float4 w4 = *(const float4*)&wt[k * 64 + ob];
        float vv[4] = {v4.x, v4.y, v4.z, v4.w};
        float ww[4] = {w4.x, w4.y, w4.z, w4.w};
#pragma unroll
        for (int i = 0; i < 4; ++i)
#pragma unroll
            for (int j = 0; j < 4; ++j)
                acc[i][j] += vv[i] * ww[j];
    }
    if (do_gelu) {
#pragma unroll
        for (int i = 0; i < 4; ++i)
#pragma unroll
            for (int j = 0; j < 4; ++j)
                acc[i][j] = gelu_f(acc[i][j]);
    }
#pragma unroll
    for (int i = 0; i < 4; ++i) {
        float4 r = {acc[i][0], acc[i][1], acc[i][2], acc[i][3]};
        *(float4*)&vout[(bS + s0 + sb + i) * 64 + ob] = r;
    }

    if (!do_proj) return;

    // ---- write v' to LDS [s][o] (vt rows 0..63, v-region dead) + stage At ----
    __syncthreads();
#pragma unroll
    for (int i = 0; i < 4; ++i) {
        float4 r = {acc[i][0], acc[i][1], acc[i][2], acc[i][3]};
        *(float4*)&vt[(sb + i) * 68 + ob] = r;
    }
    for (int idx = t; idx < 28 * 64; idx += 256) {
        int xr = idx >> 6, s = idx & 63;
        At[xr * 68 + s] = Amat[xr * SLEN + s0 + s];
    }
    __syncthreads();

    // ---- proj: Ppart[xr][c] = sum_s A[xr][s] v'[s][c] ----
    const int c = t & 63;
    const int w = t >> 6;
    float vp[16];
#pragma unroll
    for (int k = 0; k < 16; ++k)
        vp[k] = vt[(w * 16 + k) * 68 + c];

    float acc2[28];
#pragma unroll
    for (int xr = 0; xr < 28; ++xr) acc2[xr] = 0.f;
#pragma unroll
    for (int xr = 0; xr < 28; ++xr) {
        const float4* a4 = (const float4*)&At[xr * 68 + (w << 4)];
#pragma unroll
        for (int q = 0; q < 4; ++q) {
            float4 a = a4[q];
            acc2[xr] += vp[4*q+0]*a.x + vp[4*q+1]*a.y + vp[4*q+2]*a.z + vp[4*q+3]*a.w;
        }
    }
    for (int ww = 0; ww < 4; ++ww) {
        if (w == ww) {
#pragma unroll
            for (int xr = 0; xr < 28; ++xr) {
                if (ww == 0) red[xr * 64 + c] = acc2[xr];
                else         red[xr * 64 + c] += acc2[xr];
            }
        }
        __syncthreads();
    }
    for (int idx = t; idx < 28 * 64; idx += 256) {
        int xr = idx >> 6, cc = idx & 63;
        Ppart[((size_t)((b * 16 + tile) * 28 + xr)) * 64 + cc] = red[xr * 64 + cc];
    }
}

// ---------------------------------------------------------------------------
// Head, register-tiled (4s x 8h per thread):
//   hid[s][h] = sum_c v[s][c]*fc1w[c][h] + fc1b[h]
//   out[s]   += sum_h gelu(hid[s][h])*fc2w[h] + fc2b
// grid = b*16 + tile (64 s). th = t&15 (h-group of 8), tsg = t>>4 (s-group of 4).
// Shuffle-reduce over th (low 4 lane bits).
// ---------------------------------------------------------------------------
__global__ __launch_bounds__(256) void head_kernel(
    const float* __restrict__ vT, const float* __restrict__ fc1w,
    const float* __restrict__ fc1b, const float* __restrict__ fc2w,
    const float* __restrict__ fc2b, float* __restrict__ out, int accumulate)
{
    __shared__ __align__(16) float vtH[64 * 68];    // [c][s]
    __shared__ __align__(16) float fwH[64 * 128];   // [c][h]
    const int t = threadIdx.x;
    const int b    = blockIdx.x >> 4;
    const int tile = blockIdx.x & 15;
    const int s0   = tile << 6;
    const size_t bS = (size_t)b * SLEN;

    for (int idx = t; idx < 4096; idx += 256) {
        int s = idx >> 6, c = idx & 63;
        vtH[c * 68 + s] = vT[(bS + s0 + s) * 64 + c];
    }
    for (int idx = t; idx < 2048; idx += 256)
        ((float4*)fwH)[idx] = ((const float4*)fc1w)[idx];
    __syncthreads();

    const int th  = t & 15;        // h-group
    const int tsg = t >> 4;        // s-group
    const int sb  = tsg * 4;
    const int hb  = th * 8;

    float4 b1a = *(const float4*)&fc1b[hb];
    float4 b1b = *(const float4*)&fc1b[hb + 4];
    float acc[4][8];
#pragma unroll
    for (int i = 0; i < 4; ++i) {
        acc[i][0]=b1a.x; acc[i][1]=b1a.y; acc[i][2]=b1a.z; acc[i][3]=b1a.w;
        acc[i][4]=b1b.x; acc[i][5]=b1b.y; acc[i][6]=b1b.z; acc[i][7]=b1b.w;
    }

#pragma unroll 4
    for (int k = 0; k < 64; ++k) {
        float4 v4 = *(const float4*)&vtH[k * 68 + sb];
        float4 wa = *(const float4*)&fwH[k * 128 + hb];
        float4 wb = *(const float4*)&fwH[k * 128 + hb + 4];
        float vv[4] = {v4.x, v4.y, v4.z, v4.w};
        float ww[8] = {wa.x, wa.y, wa.z, wa.w, wb.x, wb.y, wb.z, wb.w};
#pragma unroll
        for (int i = 0; i < 4; ++i)
#pragma unroll
            for (int j = 0; j < 8; ++j)
                acc[i][j] += vv[i] * ww[j];
    }

    float4 w2a = *(const float4*)&fc2w[hb];
    float4 w2b = *(const float4*)&fc2w[hb + 4];
    float w2[8] = {w2a.x, w2a.y, w2a.z, w2a.w, w2b.x, w2b.y, w2b.z, w2b.w};

    float u[4];
#pragma unroll
    for (int i = 0; i < 4; ++i) {
        float s = 0.f;
#pragma unroll
        for (int j = 0; j < 8; ++j)
            s += gelu_f(acc[i][j]) * w2[j];
        u[i] = s;
    }
    // reduce over th = low 4 lane bits
#pragma unroll
    for (int i = 0; i < 4; ++i) {
        u[i] += __shfl_xor(u[i], 1, 64);
        u[i] += __shfl_xor(u[i], 2, 64);
        u[i] += __shfl_xor(u[i], 4, 64);
        u[i] += __shfl_xor(u[i], 8, 64);
    }
    if (th == 0) {
        float f2b = fc2b[0];
#pragma unroll
        for (int i = 0; i < 4; ++i) {
            size_t oidx = bS + s0 + sb + i;
            float val = u[i] + f2b;
            out[oidx] = accumulate ? (out[oidx] + val) : val;
        }
    }
}

// ---------------------------------------------------------------------------
extern "C" void kernel_launch(void* const* d_in, const int* in_sizes, int n_in,
                              void* d_out, int out_size, void* d_ws, size_t ws_size,
                              hipStream_t stream)
{
    const float* x = (const float*)d_in[0];

    float* ws    = (float*)d_ws;
    float* vA    = ws;                                  // 4,194,304 f
    float* vB    = vA + (size_t)BC * SLEN;              // 4,194,304 f
    float* Amat  = vB + (size_t)BC * SLEN;              // 28,672 f
    float* MmatT = Amat + 28 * SLEN;                    // 28,672 f
    float* Ppart = MmatT + 28 * SLEN;                   // 1,835,008 f
    float* Dbuf  = Ppart + (size_t)BDIM * 16 * 28 * 64; // 114,688 f
    float* cwT   = Dbuf + (size_t)BDIM * 28 * 64;       // 4,096 f

    precompute_A_kernel<<<256, 256, 0, stream>>>(Amat);
    precompute_M_kernel<<<7, 256, 0, stream>>>(MmatT);

    for (int br = 0; br < 2; ++br) {
        const float* fc0w = (const float*)d_in[1 + br * 10 + 0];
        const float* fc0b = (const float*)d_in[1 + br * 10 + 1];
        const float* ww1  = (const float*)d_in[1 + br * 10 + 2];
        const float* ww2  = (const float*)d_in[1 + br * 10 + 3];
        const float* cw   = (const float*)d_in[1 + br * 10 + 4];
        const float* cb   = (const float*)d_in[1 + br * 10 + 5];
        const float* fc1w = (const float*)d_in[1 + br * 10 + 6];
        const float* fc1b = (const float*)d_in[1 + br * 10 + 7];
        const float* fc2w = (const float*)d_in[1 + br * 10 + 8];
        const float* fc2b = (const float*)d_in[1 + br * 10 + 9];

        float* pv = vA;
        float* pa = vB;

        fc0proj_kernel<<<BDIM * 16, 256, 0, stream>>>(x, fc0w, fc0b, Amat, pv, Ppart);

        for (int i = 0; i < 4; ++i) {
            mix_kernel<<<225, 256, 0, stream>>>(
                Ppart, ww1 + (size_t)i * WCH * WCH * 14,
                ww2 + (size_t)i * WCH * WCH * 14,
                cw + (size_t)i * WCH * WCH, Dbuf, cwT);
            layer_kernel<<<BDIM * 16, 256, 0, stream>>>(
                pv, Dbuf, MmatT, Amat, cwT, cb + (size_t)i * WCH,
                pa, Ppart, (i < 3) ? 1 : 0, (i < 3) ? 1 : 0);
            float* tmp = pv; pv = pa; pa = tmp;
        }

        head_kernel<<<BDIM * 16, 256, 0, stream>>>(
            pv, fc1w, fc1b, fc2w, fc2b, (float*)d_out, br);
    }
}